// Round 7
// baseline (432.687 us; speedup 1.0000x reference)
//
#include <hip/hip_runtime.h>
#include <math.h>

#define BB 2048
#define TT 100
#define DD 128
#define HH 128

typedef __attribute__((ext_vector_type(8))) short bf16x8;
typedef __attribute__((ext_vector_type(4))) float f32x4;

__device__ __forceinline__ float sigm(float x) {
    return __builtin_amdgcn_rcpf(1.f + __expf(-x));
}
__device__ __forceinline__ float tanh_fast(float x) {
    x = fminf(fmaxf(x, -15.f), 15.f);
    float e = __expf(2.f * x);
    return (e - 1.f) * __builtin_amdgcn_rcpf(e + 1.f);
}
__device__ __forceinline__ short f2bf(float f) {
    union { float f; unsigned u; } v; v.f = f;
    unsigned r = v.u + 0x7FFF + ((v.u >> 16) & 1);
    return (short)(r >> 16);
}
__device__ __forceinline__ float bf2f(ushort u) {
    union { unsigned u; float f; } v; v.u = ((unsigned)u) << 16;
    return v.f;
}

// A-fragment LDS access (row-swizzled, 256B row stride)
#define RD_A(buf, kk) (*(const bf16x8*)((const char*)(buf) + arow * 256 + (((kk) * 64 + akg * 16) ^ ((arow & 7) << 4))))
#define ST_A(buf, row, c, val) (*(short*)((char*)(buf) + (row) * 256 + (((c) * 2) ^ (((row) & 7) << 4))) = (val))

// ---------------- prep: attention layer0 factorization ----------------
__global__ void k_prep(const float* __restrict__ attW0,
                       float* __restrict__ Wk, float* __restrict__ Wd, float* __restrict__ WqmC) {
    int i = blockIdx.x * 256 + threadIdx.x;
    if (i < 128 * 80) {
        int d = i / 80, j = i - d * 80;
        Wk[i]   = attW0[j * 512 + d] + attW0[j * 512 + 256 + d];
        Wd[i]   = attW0[j * 512 + 384 + d];
        WqmC[i] = attW0[j * 512 + 128 + d] - attW0[j * 512 + 256 + d];
    }
}

// ---------------- pack weights into MFMA B-fragment order (bf16) ----------------
__global__ void k_pack(const float* __restrict__ Wih, const float* __restrict__ Whh,
                       const float* __restrict__ Wr, const float* __restrict__ Wu, const float* __restrict__ Wh,
                       const float* __restrict__ attW1,
                       const float* __restrict__ phW0, const float* __restrict__ phW1,
                       ushort* __restrict__ Pgru, ushort* __restrict__ Pa1, ushort* __restrict__ Pa2,
                       ushort* __restrict__ W1bf, ushort* __restrict__ W0h, ushort* __restrict__ W1h) {
    int n = blockIdx.x * 256 + threadIdx.x;
    if (n < 98304) { // GRU: 48 tiles (0..23 Wih cols, 24..47 Whh cols), 4 k-tiles
        int tile = n >> 11, kt = (n >> 9) & 3, li = (n >> 3) & 63, e = n & 7;
        int k = kt * 32 + (li >> 4) * 8 + e;
        float s;
        if (tile < 24) { int j = tile * 16 + (li & 15); s = Wih[j * 128 + k]; }
        else           { int j = (tile - 24) * 16 + (li & 15); s = Whh[j * 128 + k]; }
        Pgru[n] = (ushort)f2bf(s);
    }
    if (n < 65536) { // AUGRU P1: 16 tiles (cols: 0..127 r, 128..255 u), 8 k-tiles
        int tile = n >> 12, kt = (n >> 9) & 7, li = (n >> 3) & 63, e = n & 7;
        int k = kt * 32 + (li >> 4) * 8 + e;
        int jj = tile * 16 + (li & 15);
        float s = (jj < 128) ? Wr[jj * 256 + k] : Wu[(jj - 128) * 256 + k];
        Pa1[n] = (ushort)f2bf(s);
    }
    if (n < 32768) { // AUGRU P2: 8 tiles (Wh cols), 8 k-tiles
        int tile = n >> 12, kt = (n >> 9) & 7, li = (n >> 3) & 63, e = n & 7;
        int k = kt * 32 + (li >> 4) * 8 + e;
        int j = tile * 16 + (li & 15);
        Pa2[n] = (ushort)f2bf(Wh[j * 256 + k]);
    }
    if (n < 4608) { // attention layer1: 3 nt x 3 kt (K=80->96, N=40->48)
        int g = n >> 9;
        int nt = g / 3, kt = g - nt * 3;
        int li = (n >> 3) & 63, e = n & 7;
        int k = kt * 32 + (li >> 4) * 8 + e;
        int j2 = nt * 16 + (li & 15);
        float s = (k < 80 && j2 < 40) ? attW1[j2 * 80 + k] : 0.f;
        W1bf[n] = (ushort)f2bf(s);
    }
    if (n < 133120) { // predict-head layer0: 13 nt x 20 kt (N=200->208, K=640)
        int g = n >> 9;
        int nt = g / 20, kt = g - nt * 20;
        int li = (n >> 3) & 63, e = n & 7;
        int k = kt * 32 + (li >> 4) * 8 + e;
        int j = nt * 16 + (li & 15);
        W0h[n] = (ushort)f2bf((j < 200) ? phW0[j * 640 + k] : 0.f);
    }
    if (n < 17920) { // predict-head layer1: 5 nt x 7 kt (N=80, K=200->224)
        int g = n >> 9;
        int nt = g / 7, kt = g - nt * 7;
        int li = (n >> 3) & 63, e = n & 7;
        int k = kt * 32 + (li >> 4) * 8 + e;
        int j = nt * 16 + (li & 15);
        W1h[n] = (ushort)f2bf((k < 200 && j < 80) ? phW1[j * 200 + k] : 0.f);
    }
}

// ---------------- per-b effective layer0 weights, bf16 fragment order ----------------
__global__ void k_weffbf(const float* __restrict__ item, const float* __restrict__ Wk,
                         const float* __restrict__ Wd, const float* __restrict__ WqmC,
                         const float* __restrict__ attb0,
                         ushort* __restrict__ Weffbf, float* __restrict__ bias2) {
    int b = blockIdx.x, tid = threadIdx.x;
    __shared__ float q[128];
    if (tid < 128) q[tid] = item[b * 128 + tid];
    __syncthreads();
    ushort* Wb = Weffbf + (size_t)b * 10240;
    for (int idx = tid; idx < 10240; idx += 256) {
        int e = idx & 7, li = (idx >> 3) & 63, kt = (idx >> 9) & 3, nt = idx >> 11;
        int d = kt * 32 + (li >> 4) * 8 + e;
        int j = nt * 16 + (li & 15);
        Wb[idx] = (ushort)f2bf(Wk[d * 80 + j] + q[d] * Wd[d * 80 + j]);
    }
    if (tid < 80) {
        float s = attb0[tid];
        for (int d = 0; d < 128; ++d) s += q[d] * WqmC[d * 80 + tid];
        bias2[b * 80 + tid] = s;
    }
}

// ---------------- GRU scan via MFMA, in-register gates, cross-step x pipelining ----------------
// 1 barrier/step. x-part MFMAs for t+1 issued after step t's barrier (off the h critical path).
__global__ __launch_bounds__(512) void k_gru_mfma(const float* __restrict__ hist,
                                                  const ushort* __restrict__ Wp,
                                                  const float* __restrict__ bih, const float* __restrict__ bhh,
                                                  const int* __restrict__ len,
                                                  ushort* __restrict__ keysbf, float* __restrict__ hsum) {
    int tid = threadIdx.x;
    int lane = tid & 63, w = tid >> 6;
    int b0 = blockIdx.x * 8;

    __shared__ ushort xbf[2][16 * 128];
    __shared__ ushort hbf[2][16 * 128];
    __shared__ int    ln_s[8];

    for (int e = tid; e < 16 * 128; e += 512) { xbf[0][e] = 0; xbf[1][e] = 0; hbf[0][e] = 0; hbf[1][e] = 0; }
    if (tid < 8) ln_s[tid] = len[b0 + tid];

    const bf16x8* Wv = (const bf16x8*)Wp;
    bf16x8 bfx[3][4], bfh[3][4];
#pragma unroll
    for (int g = 0; g < 3; ++g)
#pragma unroll
        for (int kt = 0; kt < 4; ++kt) {
            bfx[g][kt] = Wv[((g * 8 + w) * 4 + kt) * 64 + lane];
            bfh[g][kt] = Wv[(((24 + g * 8 + w)) * 4 + kt) * 64 + lane];
        }

    int arow = lane & 15, akg = lane >> 4;
    int c = w * 16 + arow;
    float birq = bih[c] + bhh[c];
    float bizq = bih[128 + c] + bhh[128 + c];
    float bin  = bih[256 + c];
    float bqn  = bhh[256 + c];
    float hold[4] = {0.f, 0.f, 0.f, 0.f};

    int srow = tid >> 6, sd0 = (tid & 63) * 2;
    const float* hsrc = &hist[(size_t)(b0 + srow) * TT * DD + sd0];
    float2 v = *(const float2*)hsrc;   // x(0)
    __syncthreads();                   // init + ln_s visible
    int Lrow = ln_s[srow];
    float sum0 = 0.f, sum1 = 0.f;
    // stage x(0) -> xbf[0]
    {
        unsigned pv = (unsigned)(unsigned short)f2bf(v.x) | ((unsigned)(unsigned short)f2bf(v.y) << 16);
        *(unsigned*)((char*)xbf[0] + srow * 256 + ((sd0 * 2) ^ ((srow & 7) << 4))) = pv;
        if (0 < Lrow) { sum0 += v.x; sum1 += v.y; }
        if (TT > 1) v = *(const float2*)(hsrc + DD);
    }
    __syncthreads();

    // preissue x-part MFMAs for t=0
    f32x4 accr, accz, accnx;
    {
        bf16x8 af[4];
#pragma unroll
        for (int kt = 0; kt < 4; ++kt) af[kt] = RD_A(xbf[0], kt);
        accr = (f32x4){0.f,0.f,0.f,0.f}; accz = accr; accnx = accr;
#pragma unroll
        for (int kt = 0; kt < 4; ++kt) {
            accr  = __builtin_amdgcn_mfma_f32_16x16x32_bf16(af[kt], bfx[0][kt], accr, 0, 0, 0);
            accz  = __builtin_amdgcn_mfma_f32_16x16x32_bf16(af[kt], bfx[1][kt], accz, 0, 0, 0);
            accnx = __builtin_amdgcn_mfma_f32_16x16x32_bf16(af[kt], bfx[2][kt], accnx, 0, 0, 0);
        }
    }

    int p = 0, q = 0;
    for (int t = 0; t < TT; ++t) {
        // stage x(t+1) -> xbf[p^1]; prefetch x(t+2)
        if (t + 1 < TT) {
            unsigned pv = (unsigned)(unsigned short)f2bf(v.x) | ((unsigned)(unsigned short)f2bf(v.y) << 16);
            *(unsigned*)((char*)xbf[p ^ 1] + srow * 256 + ((sd0 * 2) ^ ((srow & 7) << 4))) = pv;
            if (t + 1 < Lrow) { sum0 += v.x; sum1 += v.y; }
            if (t + 2 < TT) v = *(const float2*)(hsrc + (size_t)(t + 2) * DD);
        }

        // h-part MFMAs (critical path)
        bf16x8 ah[4];
#pragma unroll
        for (int kt = 0; kt < 4; ++kt) ah[kt] = RD_A(hbf[q], kt);
        f32x4 accnh = {0.f, 0.f, 0.f, 0.f};
#pragma unroll
        for (int kt = 0; kt < 4; ++kt) {
            accr  = __builtin_amdgcn_mfma_f32_16x16x32_bf16(ah[kt], bfh[0][kt], accr, 0, 0, 0);
            accz  = __builtin_amdgcn_mfma_f32_16x16x32_bf16(ah[kt], bfh[1][kt], accz, 0, 0, 0);
            accnh = __builtin_amdgcn_mfma_f32_16x16x32_bf16(ah[kt], bfh[2][kt], accnh, 0, 0, 0);
        }

        // gates
        ushort* hw = (ushort*)hbf[q ^ 1];
#pragma unroll
        for (int i = 0; i < 4; ++i) {
            float r = sigm(accr[i] + birq);
            float z = sigm(accz[i] + bizq);
            float nn = tanh_fast(accnx[i] + bin + r * (accnh[i] + bqn));
            float hnew = (1.f - z) * nn + z * hold[i];
            hold[i] = hnew;
            if (akg < 2) {
                int row = akg * 4 + i;
                short hb16 = f2bf(hnew);
                ST_A(hw, row, c, hb16);
                keysbf[((size_t)(b0 + row) * TT + t) * HH + c] = (ushort)hb16;
            }
        }
        __syncthreads();

        // preissue x-part MFMAs for t+1 (reads xbf[p^1], h-independent)
        if (t + 1 < TT) {
            bf16x8 af[4];
#pragma unroll
            for (int kt = 0; kt < 4; ++kt) af[kt] = RD_A(xbf[p ^ 1], kt);
            f32x4 ar = {0.f,0.f,0.f,0.f}, az = ar, an = ar;
#pragma unroll
            for (int kt = 0; kt < 4; ++kt) {
                ar = __builtin_amdgcn_mfma_f32_16x16x32_bf16(af[kt], bfx[0][kt], ar, 0, 0, 0);
                az = __builtin_amdgcn_mfma_f32_16x16x32_bf16(af[kt], bfx[1][kt], az, 0, 0, 0);
                an = __builtin_amdgcn_mfma_f32_16x16x32_bf16(af[kt], bfx[2][kt], an, 0, 0, 0);
            }
            accr = ar; accz = az; accnx = an;
        }
        p ^= 1; q ^= 1;
    }

    hsum[(b0 + srow) * 128 + sd0]     = sum0 / (float)Lrow;
    hsum[(b0 + srow) * 128 + sd0 + 1] = sum1 / (float)Lrow;
}

// ---------------- fused attention MLP + masked softmax + pooled (one block per b) ----------------
__global__ __launch_bounds__(512) void k_attnsoft(const ushort* __restrict__ keysbf,
                                                  const ushort* __restrict__ Weffbf,
                                                  const float* __restrict__ bias2,
                                                  const ushort* __restrict__ W1bf,
                                                  const float* __restrict__ attb1, const float* __restrict__ attW2,
                                                  const float* __restrict__ attb2,
                                                  const int* __restrict__ len,
                                                  float* __restrict__ pooled) {
    int tid = threadIdx.x;
    int lane = tid & 63, w = tid >> 6;
    int b = blockIdx.x;

    __shared__ ushort kbf[112 * 128];
    __shared__ ushort scbf[112 * 96];
    __shared__ float  bias2s[80];
    __shared__ float  b1s[48];
    __shared__ float  W2s[48];
    __shared__ float  attn_s[128];
    __shared__ float  red[128];
    __shared__ float  pred[512];

    bf16x8 bfrag0[5][4];
    bf16x8 bfrag1[3][3];
    if (w < 7) {
        const bf16x8* Wb = (const bf16x8*)(Weffbf + (size_t)b * 10240);
#pragma unroll
        for (int nt = 0; nt < 5; ++nt)
#pragma unroll
            for (int kt = 0; kt < 4; ++kt)
                bfrag0[nt][kt] = Wb[(nt * 4 + kt) * 64 + lane];
#pragma unroll
        for (int nt = 0; nt < 3; ++nt)
#pragma unroll
            for (int kt = 0; kt < 3; ++kt)
                bfrag1[nt][kt] = ((const bf16x8*)W1bf)[(nt * 3 + kt) * 64 + lane];
    }

    const ushort* ksrc = keysbf + (size_t)b * TT * 128;
    for (int e = tid; e < 3584; e += 512) {
        int row = e >> 5, c4 = e & 31;
        uint2 pv;
        if (row < TT) pv = *(const uint2*)(ksrc + row * 128 + c4 * 4);
        else { pv.x = 0; pv.y = 0; }
        *(uint2*)((char*)kbf + row * 256 + ((c4 * 8) ^ ((row & 7) << 4))) = pv;
    }
    for (int e = tid; e < 1792; e += 512) {
        int row = e >> 4, c = 80 + (e & 15);
        *(ushort*)((char*)scbf + row * 192 + ((c * 2) ^ ((row & 7) << 4))) = 0;
    }
    if (tid < 80) bias2s[tid] = bias2[b * 80 + tid];
    if (tid < 48) {
        b1s[tid] = (tid < 40) ? attb1[tid] : 0.f;
        W2s[tid] = (tid < 40) ? attW2[tid] : 0.f;
    }
    __syncthreads();

    if (w < 7) {
        int arow = lane & 15, akg = lane >> 4;
        int row = w * 16 + arow;
        bf16x8 af[4];
#pragma unroll
        for (int kt = 0; kt < 4; ++kt)
            af[kt] = *(const bf16x8*)((const char*)kbf + row * 256 + (((kt * 64 + akg * 16)) ^ ((row & 7) << 4)));
#pragma unroll
        for (int nt = 0; nt < 5; ++nt) {
            f32x4 acc = {0.f, 0.f, 0.f, 0.f};
#pragma unroll
            for (int kt = 0; kt < 4; ++kt)
                acc = __builtin_amdgcn_mfma_f32_16x16x32_bf16(af[kt], bfrag0[nt][kt], acc, 0, 0, 0);
            int col = nt * 16 + arow;
            float bcol = bias2s[col];
#pragma unroll
            for (int i = 0; i < 4; ++i) {
                int r2 = w * 16 + akg * 4 + i;
                float vsc = fmaxf(acc[i] + bcol, 0.f);
                *(short*)((char*)scbf + r2 * 192 + ((col * 2) ^ ((r2 & 7) << 4))) = f2bf(vsc);
            }
        }
    }
    __syncthreads();

    if (w < 7) {
        int arow = lane & 15, akg = lane >> 4;
        int row = w * 16 + arow;
        bf16x8 a1[3];
#pragma unroll
        for (int kt = 0; kt < 3; ++kt)
            a1[kt] = *(const bf16x8*)((const char*)scbf + row * 192 + (((kt * 64 + akg * 16)) ^ ((row & 7) << 4)));
        float pi[4] = {0.f, 0.f, 0.f, 0.f};
#pragma unroll
        for (int nt = 0; nt < 3; ++nt) {
            f32x4 acc = {0.f, 0.f, 0.f, 0.f};
#pragma unroll
            for (int kt = 0; kt < 3; ++kt)
                acc = __builtin_amdgcn_mfma_f32_16x16x32_bf16(a1[kt], bfrag1[nt][kt], acc, 0, 0, 0);
            int col = nt * 16 + arow;
            float wb = W2s[col], bb1 = b1s[col];
#pragma unroll
            for (int i = 0; i < 4; ++i)
                pi[i] += fmaxf(acc[i] + bb1, 0.f) * wb;
        }
#pragma unroll
        for (int off = 1; off < 16; off <<= 1)
#pragma unroll
            for (int i = 0; i < 4; ++i)
                pi[i] += __shfl_xor(pi[i], off);
        if ((lane & 15) == 0) {
            float b2 = attb2[0];
#pragma unroll
            for (int i = 0; i < 4; ++i) {
                int t = w * 16 + akg * 4 + i;
                if (t < 128) attn_s[t] = fmaxf(pi[i] + b2, 0.f);
            }
        }
    }
    __syncthreads();

    int L = len[b];
    if (tid < 128) red[tid] = (tid < L) ? attn_s[tid] : -INFINITY;
    __syncthreads();
    for (int o = 64; o >= 1; o >>= 1) { if (tid < o) red[tid] = fmaxf(red[tid], red[tid + o]); __syncthreads(); }
    float mx = red[0];
    __syncthreads();
    if (tid < 128) {
        float e = (tid < L) ? __expf(attn_s[tid] - mx) : 0.f;
        attn_s[tid] = e; red[tid] = e;
    }
    __syncthreads();
    for (int o = 64; o >= 1; o >>= 1) { if (tid < o) red[tid] += red[tid + o]; __syncthreads(); }
    float inv = __builtin_amdgcn_rcpf(red[0]);
    // pooled: 4 t-groups in parallel
    {
        int d = tid & 127, qd = tid >> 7;
        float p = 0.f;
        for (int t2 = qd; t2 < L; t2 += 4) {
            ushort kv = *(const ushort*)((const char*)kbf + t2 * 256 + ((d * 2) ^ ((t2 & 7) << 4)));
            p += attn_s[t2] * bf2f(kv);
        }
        pred[tid] = p;
    }
    __syncthreads();
    if (tid < 128)
        pooled[b * 128 + tid] = (pred[tid] + pred[128 + tid] + pred[256 + tid] + pred[384 + tid]) * inv;
}

// ---------------- AUGRU scan via MFMA: x from global A-frags, cross-step pipelining ----------------
__global__ __launch_bounds__(512) void k_augru_mfma(const ushort* __restrict__ keysbf,
                                                    const float* __restrict__ pooled,
                                                    const int* __restrict__ len,
                                                    const ushort* __restrict__ Wp1, const ushort* __restrict__ Wp2,
                                                    const float* __restrict__ br, const float* __restrict__ bu,
                                                    const float* __restrict__ bh,
                                                    float* __restrict__ att_feat) {
    int tid = threadIdx.x;
    int lane = tid & 63, w = tid >> 6;
    int b0 = blockIdx.x * 8;

    __shared__ ushort hbf[16 * 128], rhbf[16 * 128];
    __shared__ float as_[16];
    __shared__ int ln_s[8];

    for (int e = tid; e < 16 * 128; e += 512) { hbf[e] = 0; rhbf[e] = 0; }
    if (tid < 16) as_[tid] = 0.f;
    if (tid < 8) ln_s[tid] = len[b0 + tid];

    const bf16x8* W1v = (const bf16x8*)Wp1;
    const bf16x8* W2v = (const bf16x8*)Wp2;
    bf16x8 b1r[8], b1u[8], b2[8];
#pragma unroll
    for (int kt = 0; kt < 8; ++kt) {
        b1r[kt] = W1v[(w * 8 + kt) * 64 + lane];
        b1u[kt] = W1v[((8 + w) * 8 + kt) * 64 + lane];
        b2[kt]  = W2v[(w * 8 + kt) * 64 + lane];
    }

    int arow = lane & 15, akg = lane >> 4;
    int c = w * 16 + arow;
    float brc = br[c], buc = bu[c], bhc = bh[c];
    float hold[4] = {0.f, 0.f, 0.f, 0.f};

    // x A-fragments direct from global: lane (arow,akg) reads keys[b0+arow][t][kt*32+akg*8 ..+7]
    int rowg = b0 + arow; if (rowg > BB - 1) rowg = BB - 1;   // pad rows: clamp (result ignored)
    const ushort* xbase = keysbf + (size_t)rowg * TT * HH + akg * 8;

    bf16x8 axc[4], axn[4];
#pragma unroll
    for (int kt = 0; kt < 4; ++kt) axc[kt] = *(const bf16x8*)(xbase + kt * 32);
    float areg = (tid < 8) ? pooled[(b0 + tid) * HH + 0] : 0.f;
    if (tid < 8) as_[tid] = areg;
    float aregn = (tid < 8 && TT > 1) ? pooled[(b0 + tid) * HH + 1] : 0.f;
    __syncthreads();   // init + as_(0) visible

    // preissue P1 x-parts for t=0
    f32x4 accr = {0.f,0.f,0.f,0.f}, accu = {0.f,0.f,0.f,0.f};
#pragma unroll
    for (int kt = 0; kt < 4; ++kt) {
        accr = __builtin_amdgcn_mfma_f32_16x16x32_bf16(axc[kt], b1r[4 + kt], accr, 0, 0, 0);
        accu = __builtin_amdgcn_mfma_f32_16x16x32_bf16(axc[kt], b1u[4 + kt], accu, 0, 0, 0);
    }

    for (int t = 0; t < TT; ++t) {
        // prefetch x(t+1) frags
        if (t + 1 < TT) {
#pragma unroll
            for (int kt = 0; kt < 4; ++kt) axn[kt] = *(const bf16x8*)(xbase + (size_t)(t + 1) * HH + kt * 32);
        }

        // P1 h-part + P2 x-part (current t)
        bf16x8 ah[4];
#pragma unroll
        for (int kt = 0; kt < 4; ++kt) ah[kt] = RD_A(hbf, kt);
        f32x4 acch = {0.f,0.f,0.f,0.f};
#pragma unroll
        for (int kt = 0; kt < 4; ++kt) {
            accr = __builtin_amdgcn_mfma_f32_16x16x32_bf16(ah[kt], b1r[kt], accr, 0, 0, 0);
            accu = __builtin_amdgcn_mfma_f32_16x16x32_bf16(ah[kt], b1u[kt], accu, 0, 0, 0);
            acch = __builtin_amdgcn_mfma_f32_16x16x32_bf16(axc[kt], b2[4 + kt], acch, 0, 0, 0);
        }

        // gates1
        float u_reg[4];
#pragma unroll
        for (int i = 0; i < 4; ++i) {
            float r = sigm(accr[i] + brc);
            u_reg[i] = as_[akg * 4 + i] * sigm(accu[i] + buc);
            if (akg < 2) ST_A(rhbf, akg * 4 + i, c, f2bf(r * hold[i]));
        }
        __syncthreads();   // barrier1: rh visible

        // P2 rh-part + P1 x-parts for t+1
        bf16x8 arh[4];
#pragma unroll
        for (int kt = 0; kt < 4; ++kt) arh[kt] = RD_A(rhbf, kt);
        f32x4 accr2 = {0.f,0.f,0.f,0.f}, accu2 = {0.f,0.f,0.f,0.f};
#pragma unroll
        for (int kt = 0; kt < 4; ++kt) {
            acch = __builtin_amdgcn_mfma_f32_16x16x32_bf16(arh[kt], b2[kt], acch, 0, 0, 0);
            accr2 = __builtin_amdgcn_mfma_f32_16x16x32_bf16(axn[kt], b1r[4 + kt], accr2, 0, 0, 0);
            accu2 = __builtin_amdgcn_mfma_f32_16x16x32_bf16(axn[kt], b1u[4 + kt], accu2, 0, 0, 0);
        }

        // gates2
#pragma unroll
        for (int i = 0; i < 4; ++i) {
            float hhat = tanh_fast(acch[i] + bhc);
            float hnew = (1.f - u_reg[i]) * hold[i] + u_reg[i] * hhat;
            hold[i] = hnew;
            if (akg < 2) {
                int row = akg * 4 + i;
                ST_A(hbf, row, c, f2bf(hnew));
                if (t == ln_s[row] - 1) att_feat[(b0 + row) * HH + c] = hnew;
            }
        }
        if (tid < 8) as_[tid] = aregn;           // a(t+1)
        if (tid < 8 && t + 2 < TT) aregn = pooled[(b0 + tid) * HH + t + 2];
        __syncthreads();   // barrier2

        accr = accr2; accu = accu2;
#pragma unroll
        for (int kt = 0; kt < 4; ++kt) axc[kt] = axn[kt];
    }
}

// ---------------- fused predict head: comb -> 200 -> 80 -> 1, all sigmoid ----------------
__global__ __launch_bounds__(64) void k_head(const float* __restrict__ user, const float* __restrict__ item,
                                             const float* __restrict__ hsum, const float* __restrict__ attf,
                                             const ushort* __restrict__ W0h, const ushort* __restrict__ W1h,
                                             const float* __restrict__ phb0, const float* __restrict__ phb1,
                                             const float* __restrict__ phW2, const float* __restrict__ phb2,
                                             float* __restrict__ out) {
    int lane = threadIdx.x;
    int b0 = blockIdx.x * 16;
    __shared__ ushort xb[16 * 128];
    __shared__ ushort h1b[16 * 256];

    for (int e = lane; e < 4096; e += 64) h1b[e] = 0;

    int arow = lane & 15, akg = lane >> 4;
    f32x4 acc0[13];
#pragma unroll
    for (int nt = 0; nt < 13; ++nt) acc0[nt] = (f32x4){0.f, 0.f, 0.f, 0.f};

    for (int c = 0; c < 5; ++c) {
        for (int idx = lane; idx < 1024; idx += 64) {
            int row = idx >> 6, c2 = (idx & 63) * 2;
            int g = (b0 + row) * 128 + c2;
            float2 v;
            if (c == 0) v = *(const float2*)&user[g];
            else if (c == 1) v = *(const float2*)&item[g];
            else if (c == 2) v = *(const float2*)&hsum[g];
            else if (c == 3) { float2 a = *(const float2*)&item[g]; float2 h = *(const float2*)&hsum[g];
                               v.x = a.x * h.x; v.y = a.y * h.y; }
            else v = *(const float2*)&attf[g];
            unsigned pv = (unsigned)(unsigned short)f2bf(v.x) | ((unsigned)(unsigned short)f2bf(v.y) << 16);
            *(unsigned*)((char*)xb + row * 256 + ((c2 * 2) ^ ((row & 7) << 4))) = pv;
        }
        __syncthreads();
        bf16x8 af[4];
#pragma unroll
        for (int kt = 0; kt < 4; ++kt)
            af[kt] = *(const bf16x8*)((const char*)xb + arow * 256 + ((kt * 64 + akg * 16) ^ ((arow & 7) << 4)));
#pragma unroll
        for (int nt = 0; nt < 13; ++nt) {
#pragma unroll
            for (int kt = 0; kt < 4; ++kt) {
                int ktg = c * 4 + kt;
                bf16x8 bf = ((const bf16x8*)W0h)[(nt * 20 + ktg) * 64 + lane];
                acc0[nt] = __builtin_amdgcn_mfma_f32_16x16x32_bf16(af[kt], bf, acc0[nt], 0, 0, 0);
            }
        }
        __syncthreads();
    }

#pragma unroll
    for (int nt = 0; nt < 13; ++nt) {
        int col = nt * 16 + arow;
        if (col < 200) {
            float bb = phb0[col];
#pragma unroll
            for (int i = 0; i < 4; ++i) {
                int r2 = akg * 4 + i;
                *(short*)((char*)h1b + r2 * 512 + ((col * 2) ^ ((r2 & 7) << 4))) = f2bf(sigm(acc0[nt][i] + bb));
            }
        }
    }
    __syncthreads();

    bf16x8 a1[7];
#pragma unroll
    for (int kt = 0; kt < 7; ++kt)
        a1[kt] = *(const bf16x8*)((const char*)h1b + arow * 512 + ((kt * 64 + akg * 16) ^ ((arow & 7) << 4)));
    float pi[4] = {0.f, 0.f, 0.f, 0.f};
#pragma unroll
    for (int nt = 0; nt < 5; ++nt) {
        f32x4 acc = {0.f, 0.f, 0.f, 0.f};
#pragma unroll
        for (int kt = 0; kt < 7; ++kt)
            acc = __builtin_amdgcn_mfma_f32_16x16x32_bf16(a1[kt], ((const bf16x8*)W1h)[(nt * 7 + kt) * 64 + lane], acc, 0, 0, 0);
        int col = nt * 16 + arow;
        float b1 = phb1[col], w2v = phW2[col];
#pragma unroll
        for (int i = 0; i < 4; ++i)
            pi[i] += sigm(acc[i] + b1) * w2v;
    }
#pragma unroll
    for (int off = 1; off < 16; off <<= 1)
#pragma unroll
        for (int i = 0; i < 4; ++i)
            pi[i] += __shfl_xor(pi[i], off);
    if (arow == 0) {
        float b2 = phb2[0];
#pragma unroll
        for (int i = 0; i < 4; ++i)
            out[b0 + akg * 4 + i] = sigm(pi[i] + b2);
    }
}

extern "C" void kernel_launch(void* const* d_in, const int* in_sizes, int n_in,
                              void* d_out, int out_size, void* d_ws, size_t ws_size,
                              hipStream_t stream) {
    const float* user = (const float*)d_in[0];
    const float* hist = (const float*)d_in[1];
    const float* item = (const float*)d_in[2];
    const int* len = (const int*)d_in[4];
    const float* gWih = (const float*)d_in[5];
    const float* gWhh = (const float*)d_in[6];
    const float* gbih = (const float*)d_in[7];
    const float* gbhh = (const float*)d_in[8];
    const float* aWr = (const float*)d_in[9];
    const float* abr = (const float*)d_in[10];
    const float* aWu = (const float*)d_in[11];
    const float* abu = (const float*)d_in[12];
    const float* aWh = (const float*)d_in[13];
    const float* abh = (const float*)d_in[14];
    const float* attW0 = (const float*)d_in[15];
    const float* attb0 = (const float*)d_in[16];
    const float* attW1 = (const float*)d_in[17];
    const float* attb1 = (const float*)d_in[18];
    const float* attW2 = (const float*)d_in[19];
    const float* attb2 = (const float*)d_in[20];
    const float* phW0 = (const float*)d_in[21];
    const float* phb0 = (const float*)d_in[22];
    const float* phW1 = (const float*)d_in[23];
    const float* phb1 = (const float*)d_in[24];
    const float* phW2 = (const float*)d_in[25];
    const float* phb2 = (const float*)d_in[26];

    char* ws = (char*)d_ws;
    size_t off = 0;
    auto alloc = [&](size_t bytes) { char* p = ws + off; off += (bytes + 255) & ~(size_t)255; return p; };
    ushort* keysbf  = (ushort*)alloc((size_t)BB * TT * HH * 2);
    ushort* Weffbf  = (ushort*)alloc((size_t)BB * 10240 * 2);
    float* pooled   = (float*)alloc((size_t)BB * HH * 4);
    float* hsum     = (float*)alloc((size_t)BB * DD * 4);
    float* attf     = (float*)alloc((size_t)BB * HH * 4);
    float* Wk       = (float*)alloc(128 * 80 * 4);
    float* Wd       = (float*)alloc(128 * 80 * 4);
    float* WqmC     = (float*)alloc(128 * 80 * 4);
    float* bias2    = (float*)alloc((size_t)BB * 80 * 4);
    ushort* Pgru    = (ushort*)alloc(98304 * 2);
    ushort* Pa1     = (ushort*)alloc(65536 * 2);
    ushort* Pa2     = (ushort*)alloc(32768 * 2);
    ushort* W1bf    = (ushort*)alloc(4608 * 2);
    ushort* W0h     = (ushort*)alloc(133120 * 2);
    ushort* W1h     = (ushort*)alloc(17920 * 2);
    (void)in_sizes; (void)n_in; (void)out_size; (void)ws_size;

    k_prep<<<40, 256, 0, stream>>>(attW0, Wk, Wd, WqmC);
    k_pack<<<520, 256, 0, stream>>>(gWih, gWhh, aWr, aWu, aWh, attW1, phW0, phW1,
                                    Pgru, Pa1, Pa2, W1bf, W0h, W1h);
    k_weffbf<<<BB, 256, 0, stream>>>(item, Wk, Wd, WqmC, attb0, Weffbf, bias2);
    k_gru_mfma<<<256, 512, 0, stream>>>(hist, Pgru, gbih, gbhh, len, keysbf, hsum);
    k_attnsoft<<<BB, 512, 0, stream>>>(keysbf, Weffbf, bias2, W1bf, attb1, attW2, attb2, len, pooled);
    k_augru_mfma<<<256, 512, 0, stream>>>(keysbf, pooled, len, Pa1, Pa2, abr, abu, abh, attf);
    k_head<<<128, 64, 0, stream>>>(user, item, hsum, attf, W0h, W1h, phb0, phb1, phW2, phb2, (float*)d_out);
}

// Round 8
// 401.163 us; speedup vs baseline: 1.0786x; 1.0786x over previous
//
#include <hip/hip_runtime.h>
#include <math.h>

#define BB 2048
#define TT 100
#define DD 128
#define HH 128

typedef __attribute__((ext_vector_type(8))) short bf16x8;
typedef __attribute__((ext_vector_type(4))) float f32x4;

__device__ __forceinline__ float sigm(float x) {
    return __builtin_amdgcn_rcpf(1.f + __expf(-x));
}
__device__ __forceinline__ float tanh_fast(float x) {
    x = fminf(fmaxf(x, -15.f), 15.f);
    float e = __expf(2.f * x);
    return (e - 1.f) * __builtin_amdgcn_rcpf(e + 1.f);
}
__device__ __forceinline__ short f2bf(float f) {
    union { float f; unsigned u; } v; v.f = f;
    unsigned r = v.u + 0x7FFF + ((v.u >> 16) & 1);
    return (short)(r >> 16);
}
__device__ __forceinline__ float bf2f(ushort u) {
    union { unsigned u; float f; } v; v.u = ((unsigned)u) << 16;
    return v.f;
}

// A-fragment LDS access (row-swizzled, 256B row stride)
#define RD_A(buf, kk) (*(const bf16x8*)((const char*)(buf) + arow * 256 + (((kk) * 64 + akg * 16) ^ ((arow & 7) << 4))))
#define ST_A(buf, row, c, val) (*(short*)((char*)(buf) + (row) * 256 + (((c) * 2) ^ (((row) & 7) << 4))) = (val))

// ---------------- prep: attention layer0 factorization ----------------
__global__ void k_prep(const float* __restrict__ attW0,
                       float* __restrict__ Wk, float* __restrict__ Wd, float* __restrict__ WqmC) {
    int i = blockIdx.x * 256 + threadIdx.x;
    if (i < 128 * 80) {
        int d = i / 80, j = i - d * 80;
        Wk[i]   = attW0[j * 512 + d] + attW0[j * 512 + 256 + d];
        Wd[i]   = attW0[j * 512 + 384 + d];
        WqmC[i] = attW0[j * 512 + 128 + d] - attW0[j * 512 + 256 + d];
    }
}

// ---------------- pack weights into MFMA B-fragment order (bf16) ----------------
__global__ void k_pack(const float* __restrict__ Wih, const float* __restrict__ Whh,
                       const float* __restrict__ Wr, const float* __restrict__ Wu, const float* __restrict__ Wh,
                       const float* __restrict__ attW1,
                       const float* __restrict__ phW0, const float* __restrict__ phW1,
                       ushort* __restrict__ Pgru, ushort* __restrict__ Pa1, ushort* __restrict__ Pa2,
                       ushort* __restrict__ W1bf, ushort* __restrict__ W0h, ushort* __restrict__ W1h) {
    int n = blockIdx.x * 256 + threadIdx.x;
    if (n < 98304) { // GRU: 48 tiles (0..23 Wih cols, 24..47 Whh cols), 4 k-tiles
        int tile = n >> 11, kt = (n >> 9) & 3, li = (n >> 3) & 63, e = n & 7;
        int k = kt * 32 + (li >> 4) * 8 + e;
        float s;
        if (tile < 24) { int j = tile * 16 + (li & 15); s = Wih[j * 128 + k]; }
        else           { int j = (tile - 24) * 16 + (li & 15); s = Whh[j * 128 + k]; }
        Pgru[n] = (ushort)f2bf(s);
    }
    if (n < 65536) { // AUGRU P1: 16 tiles (cols: 0..127 r, 128..255 u), 8 k-tiles
        int tile = n >> 12, kt = (n >> 9) & 7, li = (n >> 3) & 63, e = n & 7;
        int k = kt * 32 + (li >> 4) * 8 + e;
        int jj = tile * 16 + (li & 15);
        float s = (jj < 128) ? Wr[jj * 256 + k] : Wu[(jj - 128) * 256 + k];
        Pa1[n] = (ushort)f2bf(s);
    }
    if (n < 32768) { // AUGRU P2: 8 tiles (Wh cols), 8 k-tiles
        int tile = n >> 12, kt = (n >> 9) & 7, li = (n >> 3) & 63, e = n & 7;
        int k = kt * 32 + (li >> 4) * 8 + e;
        int j = tile * 16 + (li & 15);
        Pa2[n] = (ushort)f2bf(Wh[j * 256 + k]);
    }
    if (n < 4608) { // attention layer1: 3 nt x 3 kt (K=80->96, N=40->48)
        int g = n >> 9;
        int nt = g / 3, kt = g - nt * 3;
        int li = (n >> 3) & 63, e = n & 7;
        int k = kt * 32 + (li >> 4) * 8 + e;
        int j2 = nt * 16 + (li & 15);
        float s = (k < 80 && j2 < 40) ? attW1[j2 * 80 + k] : 0.f;
        W1bf[n] = (ushort)f2bf(s);
    }
    if (n < 133120) { // predict-head layer0: 13 nt x 20 kt (N=200->208, K=640)
        int g = n >> 9;
        int nt = g / 20, kt = g - nt * 20;
        int li = (n >> 3) & 63, e = n & 7;
        int k = kt * 32 + (li >> 4) * 8 + e;
        int j = nt * 16 + (li & 15);
        W0h[n] = (ushort)f2bf((j < 200) ? phW0[j * 640 + k] : 0.f);
    }
    if (n < 17920) { // predict-head layer1: 5 nt x 7 kt (N=80, K=200->224)
        int g = n >> 9;
        int nt = g / 7, kt = g - nt * 7;
        int li = (n >> 3) & 63, e = n & 7;
        int k = kt * 32 + (li >> 4) * 8 + e;
        int j = nt * 16 + (li & 15);
        W1h[n] = (ushort)f2bf((k < 200 && j < 80) ? phW1[j * 200 + k] : 0.f);
    }
}

// ---------------- per-b effective layer0 weights, bf16 fragment order ----------------
__global__ void k_weffbf(const float* __restrict__ item, const float* __restrict__ Wk,
                         const float* __restrict__ Wd, const float* __restrict__ WqmC,
                         const float* __restrict__ attb0,
                         ushort* __restrict__ Weffbf, float* __restrict__ bias2) {
    int b = blockIdx.x, tid = threadIdx.x;
    __shared__ float q[128];
    if (tid < 128) q[tid] = item[b * 128 + tid];
    __syncthreads();
    ushort* Wb = Weffbf + (size_t)b * 10240;
    for (int idx = tid; idx < 10240; idx += 256) {
        int e = idx & 7, li = (idx >> 3) & 63, kt = (idx >> 9) & 3, nt = idx >> 11;
        int d = kt * 32 + (li >> 4) * 8 + e;
        int j = nt * 16 + (li & 15);
        Wb[idx] = (ushort)f2bf(Wk[d * 80 + j] + q[d] * Wd[d * 80 + j]);
    }
    if (tid < 80) {
        float s = attb0[tid];
        for (int d = 0; d < 128; ++d) s += q[d] * WqmC[d * 80 + tid];
        bias2[b * 80 + tid] = s;
    }
}

// ---------------- GRU scan via MFMA, in-register gates, cross-step x pipelining ----------------
__global__ __launch_bounds__(512) void k_gru_mfma(const float* __restrict__ hist,
                                                  const ushort* __restrict__ Wp,
                                                  const float* __restrict__ bih, const float* __restrict__ bhh,
                                                  const int* __restrict__ len,
                                                  ushort* __restrict__ keysbf, float* __restrict__ hsum) {
    int tid = threadIdx.x;
    int lane = tid & 63, w = tid >> 6;
    int b0 = blockIdx.x * 8;

    __shared__ ushort xbf[2][16 * 128];
    __shared__ ushort hbf[2][16 * 128];
    __shared__ int    ln_s[8];

    for (int e = tid; e < 16 * 128; e += 512) { xbf[0][e] = 0; xbf[1][e] = 0; hbf[0][e] = 0; hbf[1][e] = 0; }
    if (tid < 8) ln_s[tid] = len[b0 + tid];

    const bf16x8* Wv = (const bf16x8*)Wp;
    bf16x8 bfx[3][4], bfh[3][4];
#pragma unroll
    for (int g = 0; g < 3; ++g)
#pragma unroll
        for (int kt = 0; kt < 4; ++kt) {
            bfx[g][kt] = Wv[((g * 8 + w) * 4 + kt) * 64 + lane];
            bfh[g][kt] = Wv[(((24 + g * 8 + w)) * 4 + kt) * 64 + lane];
        }

    int arow = lane & 15, akg = lane >> 4;
    int c = w * 16 + arow;
    float birq = bih[c] + bhh[c];
    float bizq = bih[128 + c] + bhh[128 + c];
    float bin  = bih[256 + c];
    float bqn  = bhh[256 + c];
    float hold[4] = {0.f, 0.f, 0.f, 0.f};

    int srow = tid >> 6, sd0 = (tid & 63) * 2;
    const float* hsrc = &hist[(size_t)(b0 + srow) * TT * DD + sd0];
    float2 v = *(const float2*)hsrc;   // x(0)
    __syncthreads();                   // init + ln_s visible
    int Lrow = ln_s[srow];
    float sum0 = 0.f, sum1 = 0.f;
    {
        unsigned pv = (unsigned)(unsigned short)f2bf(v.x) | ((unsigned)(unsigned short)f2bf(v.y) << 16);
        *(unsigned*)((char*)xbf[0] + srow * 256 + ((sd0 * 2) ^ ((srow & 7) << 4))) = pv;
        if (0 < Lrow) { sum0 += v.x; sum1 += v.y; }
        if (TT > 1) v = *(const float2*)(hsrc + DD);
    }
    __syncthreads();

    // preissue x-part MFMAs for t=0
    f32x4 accr, accz, accnx;
    {
        bf16x8 af[4];
#pragma unroll
        for (int kt = 0; kt < 4; ++kt) af[kt] = RD_A(xbf[0], kt);
        accr = (f32x4){0.f,0.f,0.f,0.f}; accz = accr; accnx = accr;
#pragma unroll
        for (int kt = 0; kt < 4; ++kt) {
            accr  = __builtin_amdgcn_mfma_f32_16x16x32_bf16(af[kt], bfx[0][kt], accr, 0, 0, 0);
            accz  = __builtin_amdgcn_mfma_f32_16x16x32_bf16(af[kt], bfx[1][kt], accz, 0, 0, 0);
            accnx = __builtin_amdgcn_mfma_f32_16x16x32_bf16(af[kt], bfx[2][kt], accnx, 0, 0, 0);
        }
    }

    int p = 0, q = 0;
    for (int t = 0; t < TT; ++t) {
        // stage x(t+1) -> xbf[p^1]; prefetch x(t+2)
        if (t + 1 < TT) {
            unsigned pv = (unsigned)(unsigned short)f2bf(v.x) | ((unsigned)(unsigned short)f2bf(v.y) << 16);
            *(unsigned*)((char*)xbf[p ^ 1] + srow * 256 + ((sd0 * 2) ^ ((srow & 7) << 4))) = pv;
            if (t + 1 < Lrow) { sum0 += v.x; sum1 += v.y; }
            if (t + 2 < TT) v = *(const float2*)(hsrc + (size_t)(t + 2) * DD);
        }

        // h-part MFMAs (critical path)
        bf16x8 ah[4];
#pragma unroll
        for (int kt = 0; kt < 4; ++kt) ah[kt] = RD_A(hbf[q], kt);
        f32x4 accnh = {0.f, 0.f, 0.f, 0.f};
#pragma unroll
        for (int kt = 0; kt < 4; ++kt) {
            accr  = __builtin_amdgcn_mfma_f32_16x16x32_bf16(ah[kt], bfh[0][kt], accr, 0, 0, 0);
            accz  = __builtin_amdgcn_mfma_f32_16x16x32_bf16(ah[kt], bfh[1][kt], accz, 0, 0, 0);
            accnh = __builtin_amdgcn_mfma_f32_16x16x32_bf16(ah[kt], bfh[2][kt], accnh, 0, 0, 0);
        }

        // gates
        ushort* hw = (ushort*)hbf[q ^ 1];
#pragma unroll
        for (int i = 0; i < 4; ++i) {
            float r = sigm(accr[i] + birq);
            float z = sigm(accz[i] + bizq);
            float nn = tanh_fast(accnx[i] + bin + r * (accnh[i] + bqn));
            float hnew = (1.f - z) * nn + z * hold[i];
            hold[i] = hnew;
            if (akg < 2) {
                int row = akg * 4 + i;
                short hb16 = f2bf(hnew);
                ST_A(hw, row, c, hb16);
                keysbf[((size_t)(b0 + row) * TT + t) * HH + c] = (ushort)hb16;
            }
        }
        __syncthreads();

        // preissue x-part MFMAs for t+1
        if (t + 1 < TT) {
            bf16x8 af[4];
#pragma unroll
            for (int kt = 0; kt < 4; ++kt) af[kt] = RD_A(xbf[p ^ 1], kt);
            f32x4 ar = {0.f,0.f,0.f,0.f}, az = ar, an = ar;
#pragma unroll
            for (int kt = 0; kt < 4; ++kt) {
                ar = __builtin_amdgcn_mfma_f32_16x16x32_bf16(af[kt], bfx[0][kt], ar, 0, 0, 0);
                az = __builtin_amdgcn_mfma_f32_16x16x32_bf16(af[kt], bfx[1][kt], az, 0, 0, 0);
                an = __builtin_amdgcn_mfma_f32_16x16x32_bf16(af[kt], bfx[2][kt], an, 0, 0, 0);
            }
            accr = ar; accz = az; accnx = an;
        }
        p ^= 1; q ^= 1;
    }

    hsum[(b0 + srow) * 128 + sd0]     = sum0 / (float)Lrow;
    hsum[(b0 + srow) * 128 + sd0 + 1] = sum1 / (float)Lrow;
}

// ---------------- fused attention MLP + masked softmax + pooled (one block per b) ----------------
__global__ __launch_bounds__(512) void k_attnsoft(const ushort* __restrict__ keysbf,
                                                  const ushort* __restrict__ Weffbf,
                                                  const float* __restrict__ bias2,
                                                  const ushort* __restrict__ W1bf,
                                                  const float* __restrict__ attb1, const float* __restrict__ attW2,
                                                  const float* __restrict__ attb2,
                                                  const int* __restrict__ len,
                                                  float* __restrict__ pooled) {
    int tid = threadIdx.x;
    int lane = tid & 63, w = tid >> 6;
    int b = blockIdx.x;

    __shared__ ushort kbf[112 * 128];
    __shared__ ushort scbf[112 * 96];
    __shared__ float  bias2s[80];
    __shared__ float  b1s[48];
    __shared__ float  W2s[48];
    __shared__ float  attn_s[128];
    __shared__ float  red[128];
    __shared__ float  pred[512];

    bf16x8 bfrag0[5][4];
    bf16x8 bfrag1[3][3];
    if (w < 7) {
        const bf16x8* Wb = (const bf16x8*)(Weffbf + (size_t)b * 10240);
#pragma unroll
        for (int nt = 0; nt < 5; ++nt)
#pragma unroll
            for (int kt = 0; kt < 4; ++kt)
                bfrag0[nt][kt] = Wb[(nt * 4 + kt) * 64 + lane];
#pragma unroll
        for (int nt = 0; nt < 3; ++nt)
#pragma unroll
            for (int kt = 0; kt < 3; ++kt)
                bfrag1[nt][kt] = ((const bf16x8*)W1bf)[(nt * 3 + kt) * 64 + lane];
    }

    const ushort* ksrc = keysbf + (size_t)b * TT * 128;
    for (int e = tid; e < 3584; e += 512) {
        int row = e >> 5, c4 = e & 31;
        uint2 pv;
        if (row < TT) pv = *(const uint2*)(ksrc + row * 128 + c4 * 4);
        else { pv.x = 0; pv.y = 0; }
        *(uint2*)((char*)kbf + row * 256 + ((c4 * 8) ^ ((row & 7) << 4))) = pv;
    }
    for (int e = tid; e < 1792; e += 512) {
        int row = e >> 4, c = 80 + (e & 15);
        *(ushort*)((char*)scbf + row * 192 + ((c * 2) ^ ((row & 7) << 4))) = 0;
    }
    if (tid < 80) bias2s[tid] = bias2[b * 80 + tid];
    if (tid < 48) {
        b1s[tid] = (tid < 40) ? attb1[tid] : 0.f;
        W2s[tid] = (tid < 40) ? attW2[tid] : 0.f;
    }
    __syncthreads();

    if (w < 7) {
        int arow = lane & 15, akg = lane >> 4;
        int row = w * 16 + arow;
        bf16x8 af[4];
#pragma unroll
        for (int kt = 0; kt < 4; ++kt)
            af[kt] = *(const bf16x8*)((const char*)kbf + row * 256 + (((kt * 64 + akg * 16)) ^ ((row & 7) << 4)));
#pragma unroll
        for (int nt = 0; nt < 5; ++nt) {
            f32x4 acc = {0.f, 0.f, 0.f, 0.f};
#pragma unroll
            for (int kt = 0; kt < 4; ++kt)
                acc = __builtin_amdgcn_mfma_f32_16x16x32_bf16(af[kt], bfrag0[nt][kt], acc, 0, 0, 0);
            int col = nt * 16 + arow;
            float bcol = bias2s[col];
#pragma unroll
            for (int i = 0; i < 4; ++i) {
                int r2 = w * 16 + akg * 4 + i;
                float vsc = fmaxf(acc[i] + bcol, 0.f);
                *(short*)((char*)scbf + r2 * 192 + ((col * 2) ^ ((r2 & 7) << 4))) = f2bf(vsc);
            }
        }
    }
    __syncthreads();

    if (w < 7) {
        int arow = lane & 15, akg = lane >> 4;
        int row = w * 16 + arow;
        bf16x8 a1[3];
#pragma unroll
        for (int kt = 0; kt < 3; ++kt)
            a1[kt] = *(const bf16x8*)((const char*)scbf + row * 192 + (((kt * 64 + akg * 16)) ^ ((row & 7) << 4)));
        float pi[4] = {0.f, 0.f, 0.f, 0.f};
#pragma unroll
        for (int nt = 0; nt < 3; ++nt) {
            f32x4 acc = {0.f, 0.f, 0.f, 0.f};
#pragma unroll
            for (int kt = 0; kt < 3; ++kt)
                acc = __builtin_amdgcn_mfma_f32_16x16x32_bf16(a1[kt], bfrag1[nt][kt], acc, 0, 0, 0);
            int col = nt * 16 + arow;
            float wb = W2s[col], bb1 = b1s[col];
#pragma unroll
            for (int i = 0; i < 4; ++i)
                pi[i] += fmaxf(acc[i] + bb1, 0.f) * wb;
        }
#pragma unroll
        for (int off = 1; off < 16; off <<= 1)
#pragma unroll
            for (int i = 0; i < 4; ++i)
                pi[i] += __shfl_xor(pi[i], off);
        if ((lane & 15) == 0) {
            float b2 = attb2[0];
#pragma unroll
            for (int i = 0; i < 4; ++i) {
                int t = w * 16 + akg * 4 + i;
                if (t < 128) attn_s[t] = fmaxf(pi[i] + b2, 0.f);
            }
        }
    }
    __syncthreads();

    int L = len[b];
    if (tid < 128) red[tid] = (tid < L) ? attn_s[tid] : -INFINITY;
    __syncthreads();
    for (int o = 64; o >= 1; o >>= 1) { if (tid < o) red[tid] = fmaxf(red[tid], red[tid + o]); __syncthreads(); }
    float mx = red[0];
    __syncthreads();
    if (tid < 128) {
        float e = (tid < L) ? __expf(attn_s[tid] - mx) : 0.f;
        attn_s[tid] = e; red[tid] = e;
    }
    __syncthreads();
    for (int o = 64; o >= 1; o >>= 1) { if (tid < o) red[tid] += red[tid + o]; __syncthreads(); }
    float inv = __builtin_amdgcn_rcpf(red[0]);
    {
        int d = tid & 127, qd = tid >> 7;
        float p = 0.f;
        for (int t2 = qd; t2 < L; t2 += 4) {
            ushort kv = *(const ushort*)((const char*)kbf + t2 * 256 + ((d * 2) ^ ((t2 & 7) << 4)));
            p += attn_s[t2] * bf2f(kv);
        }
        pred[tid] = p;
    }
    __syncthreads();
    if (tid < 128)
        pooled[b * 128 + tid] = (pred[tid] + pred[128 + tid] + pred[256 + tid] + pred[384 + tid]) * inv;
}

// ---------------- AUGRU scan via MFMA: LDS-staged x, cross-step x-part preissue ----------------
__global__ __launch_bounds__(512) void k_augru_mfma(const ushort* __restrict__ keysbf,
                                                    const float* __restrict__ pooled,
                                                    const int* __restrict__ len,
                                                    const ushort* __restrict__ Wp1, const ushort* __restrict__ Wp2,
                                                    const float* __restrict__ br, const float* __restrict__ bu,
                                                    const float* __restrict__ bh,
                                                    float* __restrict__ att_feat) {
    int tid = threadIdx.x;
    int lane = tid & 63, w = tid >> 6;
    int b0 = blockIdx.x * 8;

    __shared__ ushort hbf[16 * 128], rhbf[16 * 128];
    __shared__ ushort xbf[2][16 * 128];
    __shared__ float as_[16];
    __shared__ int ln_s[8];

    for (int e = tid; e < 16 * 128; e += 512) { hbf[e] = 0; rhbf[e] = 0; xbf[0][e] = 0; xbf[1][e] = 0; }
    if (tid < 16) as_[tid] = 0.f;
    if (tid < 8) ln_s[tid] = len[b0 + tid];

    const bf16x8* W1v = (const bf16x8*)Wp1;
    const bf16x8* W2v = (const bf16x8*)Wp2;
    bf16x8 b1r[8], b1u[8], b2[8];
#pragma unroll
    for (int kt = 0; kt < 8; ++kt) {
        b1r[kt] = W1v[(w * 8 + kt) * 64 + lane];
        b1u[kt] = W1v[((8 + w) * 8 + kt) * 64 + lane];
        b2[kt]  = W2v[(w * 8 + kt) * 64 + lane];
    }

    int arow = lane & 15, akg = lane >> 4;
    int c = w * 16 + arow;
    float brc = br[c], buc = bu[c], bhc = bh[c];
    float hold[4] = {0.f, 0.f, 0.f, 0.f};

    int srow = tid >> 6, sd0 = (tid & 63) * 2;
    const ushort* xsrc = &keysbf[(size_t)(b0 + srow) * TT * HH + sd0];
    unsigned v0 = *(const unsigned*)xsrc;            // x(0)
    float areg = (tid < 8) ? pooled[(b0 + tid) * HH + 0] : 0.f;
    __syncthreads();                                  // init visible
    *(unsigned*)((char*)xbf[0] + srow * 256 + ((sd0 * 2) ^ ((srow & 7) << 4))) = v0;
    if (tid < 8) as_[tid] = areg;
    unsigned vnext = (TT > 1) ? *(const unsigned*)(xsrc + (size_t)1 * HH) : 0u;
    float aregn = (tid < 8 && TT > 1) ? pooled[(b0 + tid) * HH + 1] : 0.f;
    __syncthreads();

    // preissue x-parts for t=0: P1 (accr,accu) + P2 x-part (acchx)
    f32x4 accr = {0.f,0.f,0.f,0.f}, accu = {0.f,0.f,0.f,0.f}, acchx = {0.f,0.f,0.f,0.f};
    {
        bf16x8 af[4];
#pragma unroll
        for (int kt = 0; kt < 4; ++kt) af[kt] = RD_A(xbf[0], kt);
#pragma unroll
        for (int kt = 0; kt < 4; ++kt) {
            accr  = __builtin_amdgcn_mfma_f32_16x16x32_bf16(af[kt], b1r[4 + kt], accr, 0, 0, 0);
            accu  = __builtin_amdgcn_mfma_f32_16x16x32_bf16(af[kt], b1u[4 + kt], accu, 0, 0, 0);
            acchx = __builtin_amdgcn_mfma_f32_16x16x32_bf16(af[kt], b2[4 + kt], acchx, 0, 0, 0);
        }
    }

    int p = 0;
    for (int t = 0; t < TT; ++t) {
        // stage x(t+1) -> xbf[p^1]; prefetch x(t+2)
        if (t + 1 < TT) {
            *(unsigned*)((char*)xbf[p ^ 1] + srow * 256 + ((sd0 * 2) ^ ((srow & 7) << 4))) = vnext;
            if (t + 2 < TT) vnext = *(const unsigned*)(xsrc + (size_t)(t + 2) * HH);
        }

        // P1 h-part (critical path: 4-deep chains)
        bf16x8 ah[4];
#pragma unroll
        for (int kt = 0; kt < 4; ++kt) ah[kt] = RD_A(hbf, kt);
#pragma unroll
        for (int kt = 0; kt < 4; ++kt) {
            accr = __builtin_amdgcn_mfma_f32_16x16x32_bf16(ah[kt], b1r[kt], accr, 0, 0, 0);
            accu = __builtin_amdgcn_mfma_f32_16x16x32_bf16(ah[kt], b1u[kt], accu, 0, 0, 0);
        }

        // gates1
        float u_reg[4];
#pragma unroll
        for (int i = 0; i < 4; ++i) {
            float r = sigm(accr[i] + brc);
            u_reg[i] = as_[akg * 4 + i] * sigm(accu[i] + buc);
            if (akg < 2) ST_A(rhbf, akg * 4 + i, c, f2bf(r * hold[i]));
        }
        __syncthreads();   // barrier1: rh visible

        // P2 rh-part + preissue next step x-parts
        bf16x8 arh[4];
#pragma unroll
        for (int kt = 0; kt < 4; ++kt) arh[kt] = RD_A(rhbf, kt);
        f32x4 acch = acchx;
        f32x4 accr2 = {0.f,0.f,0.f,0.f}, accu2 = {0.f,0.f,0.f,0.f}, acchx2 = {0.f,0.f,0.f,0.f};
#pragma unroll
        for (int kt = 0; kt < 4; ++kt)
            acch = __builtin_amdgcn_mfma_f32_16x16x32_bf16(arh[kt], b2[kt], acch, 0, 0, 0);
        if (t + 1 < TT) {
            bf16x8 axn[4];
#pragma unroll
            for (int kt = 0; kt < 4; ++kt) axn[kt] = RD_A(xbf[p ^ 1], kt);
#pragma unroll
            for (int kt = 0; kt < 4; ++kt) {
                accr2  = __builtin_amdgcn_mfma_f32_16x16x32_bf16(axn[kt], b1r[4 + kt], accr2, 0, 0, 0);
                accu2  = __builtin_amdgcn_mfma_f32_16x16x32_bf16(axn[kt], b1u[4 + kt], accu2, 0, 0, 0);
                acchx2 = __builtin_amdgcn_mfma_f32_16x16x32_bf16(axn[kt], b2[4 + kt], acchx2, 0, 0, 0);
            }
        }

        // gates2
#pragma unroll
        for (int i = 0; i < 4; ++i) {
            float hhat = tanh_fast(acch[i] + bhc);
            float hnew = (1.f - u_reg[i]) * hold[i] + u_reg[i] * hhat;
            hold[i] = hnew;
            if (akg < 2) {
                int row = akg * 4 + i;
                ST_A(hbf, row, c, f2bf(hnew));
                if (t == ln_s[row] - 1) att_feat[(b0 + row) * HH + c] = hnew;
            }
        }
        if (tid < 8) as_[tid] = aregn;           // a(t+1)
        if (tid < 8 && t + 2 < TT) aregn = pooled[(b0 + tid) * HH + t + 2];
        __syncthreads();   // barrier2

        accr = accr2; accu = accu2; acchx = acchx2;
        p ^= 1;
    }
}

// ---------------- fused predict head: comb -> 200 -> 80 -> 1, all sigmoid ----------------
__global__ __launch_bounds__(64) void k_head(const float* __restrict__ user, const float* __restrict__ item,
                                             const float* __restrict__ hsum, const float* __restrict__ attf,
                                             const ushort* __restrict__ W0h, const ushort* __restrict__ W1h,
                                             const float* __restrict__ phb0, const float* __restrict__ phb1,
                                             const float* __restrict__ phW2, const float* __restrict__ phb2,
                                             float* __restrict__ out) {
    int lane = threadIdx.x;
    int b0 = blockIdx.x * 16;
    __shared__ ushort xb[16 * 128];
    __shared__ ushort h1b[16 * 256];

    for (int e = lane; e < 4096; e += 64) h1b[e] = 0;

    int arow = lane & 15, akg = lane >> 4;
    f32x4 acc0[13];
#pragma unroll
    for (int nt = 0; nt < 13; ++nt) acc0[nt] = (f32x4){0.f, 0.f, 0.f, 0.f};

    for (int c = 0; c < 5; ++c) {
        for (int idx = lane; idx < 1024; idx += 64) {
            int row = idx >> 6, c2 = (idx & 63) * 2;
            int g = (b0 + row) * 128 + c2;
            float2 v;
            if (c == 0) v = *(const float2*)&user[g];
            else if (c == 1) v = *(const float2*)&item[g];
            else if (c == 2) v = *(const float2*)&hsum[g];
            else if (c == 3) { float2 a = *(const float2*)&item[g]; float2 h = *(const float2*)&hsum[g];
                               v.x = a.x * h.x; v.y = a.y * h.y; }
            else v = *(const float2*)&attf[g];
            unsigned pv = (unsigned)(unsigned short)f2bf(v.x) | ((unsigned)(unsigned short)f2bf(v.y) << 16);
            *(unsigned*)((char*)xb + row * 256 + ((c2 * 2) ^ ((row & 7) << 4))) = pv;
        }
        __syncthreads();
        bf16x8 af[4];
#pragma unroll
        for (int kt = 0; kt < 4; ++kt)
            af[kt] = *(const bf16x8*)((const char*)xb + arow * 256 + ((kt * 64 + akg * 16) ^ ((arow & 7) << 4)));
#pragma unroll
        for (int nt = 0; nt < 13; ++nt) {
#pragma unroll
            for (int kt = 0; kt < 4; ++kt) {
                int ktg = c * 4 + kt;
                bf16x8 bf = ((const bf16x8*)W0h)[(nt * 20 + ktg) * 64 + lane];
                acc0[nt] = __builtin_amdgcn_mfma_f32_16x16x32_bf16(af[kt], bf, acc0[nt], 0, 0, 0);
            }
        }
        __syncthreads();
    }

#pragma unroll
    for (int nt = 0; nt < 13; ++nt) {
        int col = nt * 16 + arow;
        if (col < 200) {
            float bb = phb0[col];
#pragma unroll
            for (int i = 0; i < 4; ++i) {
                int r2 = akg * 4 + i;
                *(short*)((char*)h1b + r2 * 512 + ((col * 2) ^ ((r2 & 7) << 4))) = f2bf(sigm(acc0[nt][i] + bb));
            }
        }
    }
    __syncthreads();

    bf16x8 a1[7];
#pragma unroll
    for (int kt = 0; kt < 7; ++kt)
        a1[kt] = *(const bf16x8*)((const char*)h1b + arow * 512 + ((kt * 64 + akg * 16) ^ ((arow & 7) << 4)));
    float pi[4] = {0.f, 0.f, 0.f, 0.f};
#pragma unroll
    for (int nt = 0; nt < 5; ++nt) {
        f32x4 acc = {0.f, 0.f, 0.f, 0.f};
#pragma unroll
        for (int kt = 0; kt < 7; ++kt)
            acc = __builtin_amdgcn_mfma_f32_16x16x32_bf16(a1[kt], ((const bf16x8*)W1h)[(nt * 7 + kt) * 64 + lane], acc, 0, 0, 0);
        int col = nt * 16 + arow;
        float b1 = phb1[col], w2v = phW2[col];
#pragma unroll
        for (int i = 0; i < 4; ++i)
            pi[i] += sigm(acc[i] + b1) * w2v;
    }
#pragma unroll
    for (int off = 1; off < 16; off <<= 1)
#pragma unroll
        for (int i = 0; i < 4; ++i)
            pi[i] += __shfl_xor(pi[i], off);
    if (arow == 0) {
        float b2 = phb2[0];
#pragma unroll
        for (int i = 0; i < 4; ++i)
            out[b0 + akg * 4 + i] = sigm(pi[i] + b2);
    }
}

extern "C" void kernel_launch(void* const* d_in, const int* in_sizes, int n_in,
                              void* d_out, int out_size, void* d_ws, size_t ws_size,
                              hipStream_t stream) {
    const float* user = (const float*)d_in[0];
    const float* hist = (const float*)d_in[1];
    const float* item = (const float*)d_in[2];
    const int* len = (const int*)d_in[4];
    const float* gWih = (const float*)d_in[5];
    const float* gWhh = (const float*)d_in[6];
    const float* gbih = (const float*)d_in[7];
    const float* gbhh = (const float*)d_in[8];
    const float* aWr = (const float*)d_in[9];
    const float* abr = (const float*)d_in[10];
    const float* aWu = (const float*)d_in[11];
    const float* abu = (const float*)d_in[12];
    const float* aWh = (const float*)d_in[13];
    const float* abh = (const float*)d_in[14];
    const float* attW0 = (const float*)d_in[15];
    const float* attb0 = (const float*)d_in[16];
    const float* attW1 = (const float*)d_in[17];
    const float* attb1 = (const float*)d_in[18];
    const float* attW2 = (const float*)d_in[19];
    const float* attb2 = (const float*)d_in[20];
    const float* phW0 = (const float*)d_in[21];
    const float* phb0 = (const float*)d_in[22];
    const float* phW1 = (const float*)d_in[23];
    const float* phb1 = (const float*)d_in[24];
    const float* phW2 = (const float*)d_in[25];
    const float* phb2 = (const float*)d_in[26];

    char* ws = (char*)d_ws;
    size_t off = 0;
    auto alloc = [&](size_t bytes) { char* p = ws + off; off += (bytes + 255) & ~(size_t)255; return p; };
    ushort* keysbf  = (ushort*)alloc((size_t)BB * TT * HH * 2);
    ushort* Weffbf  = (ushort*)alloc((size_t)BB * 10240 * 2);
    float* pooled   = (float*)alloc((size_t)BB * HH * 4);
    float* hsum     = (float*)alloc((size_t)BB * DD * 4);
    float* attf     = (float*)alloc((size_t)BB * HH * 4);
    float* Wk       = (float*)alloc(128 * 80 * 4);
    float* Wd       = (float*)alloc(128 * 80 * 4);
    float* WqmC     = (float*)alloc(128 * 80 * 4);
    float* bias2    = (float*)alloc((size_t)BB * 80 * 4);
    ushort* Pgru    = (ushort*)alloc(98304 * 2);
    ushort* Pa1     = (ushort*)alloc(65536 * 2);
    ushort* Pa2     = (ushort*)alloc(32768 * 2);
    ushort* W1bf    = (ushort*)alloc(4608 * 2);
    ushort* W0h     = (ushort*)alloc(133120 * 2);
    ushort* W1h     = (ushort*)alloc(17920 * 2);
    (void)in_sizes; (void)n_in; (void)out_size; (void)ws_size;

    k_prep<<<40, 256, 0, stream>>>(attW0, Wk, Wd, WqmC);
    k_pack<<<520, 256, 0, stream>>>(gWih, gWhh, aWr, aWu, aWh, attW1, phW0, phW1,
                                    Pgru, Pa1, Pa2, W1bf, W0h, W1h);
    k_weffbf<<<BB, 256, 0, stream>>>(item, Wk, Wd, WqmC, attb0, Weffbf, bias2);
    k_gru_mfma<<<256, 512, 0, stream>>>(hist, Pgru, gbih, gbhh, len, keysbf, hsum);
    k_attnsoft<<<BB, 512, 0, stream>>>(keysbf, Weffbf, bias2, W1bf, attb1, attW2, attb2, len, pooled);
    k_augru_mfma<<<256, 512, 0, stream>>>(keysbf, pooled, len, Pa1, Pa2, abr, abu, abh, attf);
    k_head<<<128, 64, 0, stream>>>(user, item, hsum, attf, W0h, W1h, phb0, phb1, phW2, phb2, (float*)d_out);
}